// Round 2
// baseline (1234.631 us; speedup 1.0000x reference)
//
#include <hip/hip_runtime.h>

#define T_    128
#define B_    64
#define H_    2048
#define L_    4
#define C_    10
#define BN_EPS 1e-5f

typedef __attribute__((ext_vector_type(8))) short bf16x8;
typedef __attribute__((ext_vector_type(4))) float f32x4;

__device__ inline short f2bf(float f) {
    union { float f; unsigned u; } v; v.f = f;
    unsigned r = (v.u + 0x7FFFu + ((v.u >> 16) & 1u)) >> 16;
    return (short)r;
}

// ---------------------------------------------------------------------------
// Z[M,N] = bn(A)[M,K] @ W[N,K]^T + bias[N]   (fp32 in, fp32 out, bf16 MFMA)
//   bn(A)[m,k] = A[m,k]*bnscale[k] + bnshift[k]   (identity if bnscale==nullptr)
// 128x128 tile, BK=32, 256 threads = 4 waves (2x2), 64x64 per wave.
// K may be < Kpad (zero-padded); Kpad % 32 == 0, K % 4 == 0.
// ---------------------------------------------------------------------------
__global__ __launch_bounds__(256) void gemm_bf16(
    const float* __restrict__ A, const float* __restrict__ W,
    const float* __restrict__ bias,
    const float* __restrict__ bnscale, const float* __restrict__ bnshift,
    float* __restrict__ Z, int M, int N, int K, int Kpad)
{
    // padded LDS: row stride 40 bf16 = 80B -> only 2-way bank aliasing on b128 reads
    __shared__ short As[128 * 40];
    __shared__ short Bs[128 * 40];

    const int tid  = threadIdx.x;
    const int m0   = blockIdx.y * 128;
    const int n0   = blockIdx.x * 128;

    // loader mapping: 2 threads per row, 16 floats each
    const int lrow = tid >> 1;
    const int lkc  = (tid & 1) * 16;

    // wave / fragment mapping
    const int wid  = tid >> 6;
    const int lane = tid & 63;
    const int wm   = (wid >> 1) * 64;
    const int wn   = (wid & 1) * 64;
    const int fr   = lane & 15;        // fragment row (A) / col (B)
    const int fk   = (lane >> 4) * 8;  // k-slot offset

    f32x4 acc[4][4];
#pragma unroll
    for (int m = 0; m < 4; ++m)
#pragma unroll
        for (int n = 0; n < 4; ++n)
            acc[m][n] = (f32x4){0.f, 0.f, 0.f, 0.f};

    const float* Arow = A + (size_t)(m0 + lrow) * K;
    const float* Wrow = W + (size_t)(n0 + lrow) * K;

    for (int k0 = 0; k0 < Kpad; k0 += 32) {
        // ---- stage A (with BN affine), fp32 -> bf16 ----
#pragma unroll
        for (int i = 0; i < 4; ++i) {
            const int k = k0 + lkc + i * 4;
            float4 a = make_float4(0.f, 0.f, 0.f, 0.f);
            if (k < K) {
                a = *(const float4*)(Arow + k);
                if (bnscale) {
                    a.x = a.x * bnscale[k + 0] + bnshift[k + 0];
                    a.y = a.y * bnscale[k + 1] + bnshift[k + 1];
                    a.z = a.z * bnscale[k + 2] + bnshift[k + 2];
                    a.w = a.w * bnscale[k + 3] + bnshift[k + 3];
                }
            }
            short4 s;
            s.x = f2bf(a.x); s.y = f2bf(a.y); s.z = f2bf(a.z); s.w = f2bf(a.w);
            *(short4*)&As[lrow * 40 + lkc + i * 4] = s;
        }
        // ---- stage B (weights), fp32 -> bf16 ----
#pragma unroll
        for (int i = 0; i < 4; ++i) {
            const int k = k0 + lkc + i * 4;
            float4 b = make_float4(0.f, 0.f, 0.f, 0.f);
            if (k < K) b = *(const float4*)(Wrow + k);
            short4 s;
            s.x = f2bf(b.x); s.y = f2bf(b.y); s.z = f2bf(b.z); s.w = f2bf(b.w);
            *(short4*)&Bs[lrow * 40 + lkc + i * 4] = s;
        }
        __syncthreads();

        bf16x8 af[4], bfr[4];
#pragma unroll
        for (int m = 0; m < 4; ++m)
            af[m] = *(const bf16x8*)&As[(wm + m * 16 + fr) * 40 + fk];
#pragma unroll
        for (int n = 0; n < 4; ++n)
            bfr[n] = *(const bf16x8*)&Bs[(wn + n * 16 + fr) * 40 + fk];

#pragma unroll
        for (int m = 0; m < 4; ++m)
#pragma unroll
            for (int n = 0; n < 4; ++n)
                acc[m][n] = __builtin_amdgcn_mfma_f32_16x16x32_bf16(
                    af[m], bfr[n], acc[m][n], 0, 0, 0);
        __syncthreads();
    }

    // ---- epilogue: D mapping col=lane&15, row=(lane>>4)*4+r (m89/m91-verified) ----
    const int orow = (lane >> 4) * 4;
#pragma unroll
    for (int m = 0; m < 4; ++m) {
#pragma unroll
        for (int n = 0; n < 4; ++n) {
            const int col = n0 + wn + n * 16 + fr;
            const float bsum = bias[col];
#pragma unroll
            for (int r = 0; r < 4; ++r) {
                const int row = m0 + wm + m * 16 + orow + r;
                Z[(size_t)row * N + col] = acc[m][n][r] + bsum;
            }
        }
    }
}

// ---------------------------------------------------------------------------
// IndRNN scan (in-place) + BN stats accumulation. One thread per (b,h).
// ---------------------------------------------------------------------------
__global__ __launch_bounds__(256) void scan_bn_stats(
    float* __restrict__ Z, const float* __restrict__ u,
    float* __restrict__ sum, float* __restrict__ sumsq)
{
    const int idx = blockIdx.x * blockDim.x + threadIdx.x;   // b*H + h
    const int h = idx & (H_ - 1);
    const float uu = u[h];
    float hprev = 0.f, s1 = 0.f, s2 = 0.f;
#pragma unroll 4
    for (int t = 0; t < T_; ++t) {
        const size_t off = (size_t)t * (B_ * H_) + idx;
        float z = Z[off];
        float hv = z + uu * hprev;
        hv = hv > 0.f ? hv : 0.f;
        Z[off] = hv;
        hprev = hv;
        s1 += hv;
        s2 += hv * hv;
    }
    atomicAdd(&sum[h], s1);
    atomicAdd(&sumsq[h], s2);
}

// ---------------------------------------------------------------------------
__global__ void bn_finalize(
    const float* __restrict__ sum, const float* __restrict__ sumsq,
    const float* __restrict__ gamma, const float* __restrict__ beta,
    float* __restrict__ scale, float* __restrict__ shift)
{
    const int h = blockIdx.x * blockDim.x + threadIdx.x;
    if (h >= H_) return;
    const float inv_n = 1.f / (float)(T_ * B_);
    const float m = sum[h] * inv_n;
    const float v = sumsq[h] * inv_n - m * m;
    const float s = gamma[h] * rsqrtf(v + BN_EPS);
    scale[h] = s;
    shift[h] = beta[h] - m * s;
}

// ---------------------------------------------------------------------------
// out[b,c] = sum_h bn(Hlast[b,h]) * Wlast[c,h] + blast[c]; one wave per (b,c).
// ---------------------------------------------------------------------------
__global__ __launch_bounds__(256) void final_proj(
    const float* __restrict__ Hlast, const float* __restrict__ scale,
    const float* __restrict__ shift, const float* __restrict__ Wlast,
    const float* __restrict__ blast, float* __restrict__ out)
{
    const int wave = (blockIdx.x * blockDim.x + threadIdx.x) >> 6;
    const int lane = threadIdx.x & 63;
    if (wave >= B_ * C_) return;
    const int b = wave / C_;
    const int c = wave % C_;
    float acc = 0.f;
    for (int h = lane; h < H_; h += 64) {
        float hv = Hlast[(size_t)b * H_ + h] * scale[h] + shift[h];
        acc += hv * Wlast[(size_t)c * H_ + h];
    }
#pragma unroll
    for (int o = 32; o > 0; o >>= 1) acc += __shfl_down(acc, o);
    if (lane == 0) out[(size_t)b * C_ + c] = acc + blast[c];
}

// ---------------------------------------------------------------------------
extern "C" void kernel_launch(void* const* d_in, const int* in_sizes, int n_in,
                              void* d_out, int out_size, void* d_ws, size_t ws_size,
                              hipStream_t stream)
{
    const float* x      = (const float*)d_in[0];  // [T,B,IN,ND] = [8192,144]
    const float* W0     = (const float*)d_in[1];  // [H,144]
    const float* Ws     = (const float*)d_in[2];  // [3,H,H]
    const float* bs     = (const float*)d_in[3];  // [4,H]
    const float* us     = (const float*)d_in[4];  // [4,H]
    const float* gammas = (const float*)d_in[5];  // [4,H]
    const float* betas  = (const float*)d_in[6];  // [4,H]
    const float* Wlast  = (const float*)d_in[7];  // [C,H]
    const float* blast  = (const float*)d_in[8];  // [C]
    float* out = (float*)d_out;

    const size_t buf_elems = (size_t)T_ * B_ * H_;           // 16M floats = 64MB
    float* buf0    = (float*)d_ws;
    float* buf1    = buf0 + buf_elems;
    float* sum     = buf1 + buf_elems;
    float* sumsq   = sum + H_;
    float* bnscale = sumsq + H_;
    float* bnshift = bnscale + H_;

    const int M = T_ * B_;                   // 8192
    const dim3 gemm_grid(H_ / 128, M / 128); // (16, 64)

    // layer 0 projection: K = 144 (pad to 160), no BN on input
    gemm_bf16<<<gemm_grid, 256, 0, stream>>>(x, W0, bs, nullptr, nullptr,
                                             buf0, M, H_, 144, 160);

    float* cur = buf0;
    float* nxt = buf1;
    for (int l = 0; l < L_; ++l) {
        hipMemsetAsync(sum, 0, 2 * H_ * sizeof(float), stream);
        scan_bn_stats<<<(B_ * H_) / 256, 256, 0, stream>>>(cur, us + l * H_, sum, sumsq);
        bn_finalize<<<H_ / 256, 256, 0, stream>>>(sum, sumsq,
                                                  gammas + l * H_, betas + l * H_,
                                                  bnscale, bnshift);
        if (l < L_ - 1) {
            gemm_bf16<<<gemm_grid, 256, 0, stream>>>(cur, Ws + (size_t)l * H_ * H_,
                                                     bs + (l + 1) * H_,
                                                     bnscale, bnshift,
                                                     nxt, M, H_, H_, H_);
            float* tmp = cur; cur = nxt; nxt = tmp;
        }
    }

    final_proj<<<(B_ * C_ * 64 + 255) / 256, 256, 0, stream>>>(
        cur + (size_t)(T_ - 1) * B_ * H_, bnscale, bnshift, Wlast, blast, out);
}

// Round 3
// 599.992 us; speedup vs baseline: 2.0577x; 2.0577x over previous
//
#include <hip/hip_runtime.h>

#define T_    128
#define B_    64
#define H_    2048
#define L_    4
#define C_    10
#define BN_EPS 1e-5f
#define K0REAL 144
#define K0PAD  160

typedef __attribute__((ext_vector_type(8))) short bf16x8;
typedef __attribute__((ext_vector_type(4))) float f32x4;

__device__ __forceinline__ short f2bf(float f) {
    union { float f; unsigned u; } v; v.f = f;
    unsigned r = (v.u + 0x7FFFu + ((v.u >> 16) & 1u)) >> 16;
    return (short)r;
}

__device__ __forceinline__ void gload16(const short* g, short* l) {
    __builtin_amdgcn_global_load_lds(
        (const __attribute__((address_space(1))) void*)g,
        (__attribute__((address_space(3))) void*)l, 16, 0, 0);
}

// ---------------------------------------------------------------------------
// Z[M,N] = A[M,Kb](bf16) @ Bw[N,Kb](bf16)^T + bias[N]  -> fp32
// m97 structure: 128x128 tile, BK=32, 4 waves (2x2), global_load_lds width=16.
// ---------------------------------------------------------------------------
__global__ __launch_bounds__(256) void gemm_bf16_lds(
    const short* __restrict__ A, const short* __restrict__ Bw,
    const float* __restrict__ bias,
    float* __restrict__ Z, int M, int N, int Kb)
{
    __shared__ short As[128 * 32];   // 8KB, linear [row][k]
    __shared__ short Bs[128 * 32];   // 8KB

    const int tid = threadIdx.x;

    // bijective XCD swizzle (nwg = 1024, 1024 % 8 == 0)
    const int nwg = gridDim.x * gridDim.y;
    int lin = blockIdx.y * gridDim.x + blockIdx.x;
    lin = (lin & 7) * (nwg >> 3) + (lin >> 3);
    const int bx = lin % gridDim.x;
    const int by = lin / gridDim.x;

    const int m0 = by * 128;
    const int n0 = bx * 128;

    // staging map: thread t -> row = t>>2 (plus 64 on 2nd issue), cols (t&3)*8..+8
    const int srow = tid >> 2;
    const int scol = (tid & 3) * 8;

    // wave / fragment map (verified in round 2)
    const int wid  = tid >> 6;
    const int lane = tid & 63;
    const int wm   = (wid >> 1) * 64;
    const int wn   = (wid & 1) * 64;
    const int fr   = lane & 15;
    const int fk   = (lane >> 4) * 8;

    f32x4 acc[4][4];
#pragma unroll
    for (int m = 0; m < 4; ++m)
#pragma unroll
        for (int n = 0; n < 4; ++n)
            acc[m][n] = (f32x4){0.f, 0.f, 0.f, 0.f};

    const short* Abase = A + (size_t)m0 * Kb;
    const short* Bbase = Bw + (size_t)n0 * Kb;

    for (int k0 = 0; k0 < Kb; k0 += 32) {
        gload16(Abase + (size_t)srow        * Kb + k0 + scol, &As[tid * 8]);
        gload16(Abase + (size_t)(srow + 64) * Kb + k0 + scol, &As[2048 + tid * 8]);
        gload16(Bbase + (size_t)srow        * Kb + k0 + scol, &Bs[tid * 8]);
        gload16(Bbase + (size_t)(srow + 64) * Kb + k0 + scol, &Bs[2048 + tid * 8]);
        __syncthreads();   // compiler drains vmcnt before barrier

        bf16x8 af[4], bfv[4];
#pragma unroll
        for (int m = 0; m < 4; ++m)
            af[m] = *(const bf16x8*)&As[(wm + m * 16 + fr) * 32 + fk];
#pragma unroll
        for (int n = 0; n < 4; ++n)
            bfv[n] = *(const bf16x8*)&Bs[(wn + n * 16 + fr) * 32 + fk];

#pragma unroll
        for (int m = 0; m < 4; ++m)
#pragma unroll
            for (int n = 0; n < 4; ++n)
                acc[m][n] = __builtin_amdgcn_mfma_f32_16x16x32_bf16(
                    af[m], bfv[n], acc[m][n], 0, 0, 0);
        __syncthreads();
    }

    // epilogue: C/D map col=lane&15, row=(lane>>4)*4+r
    const int orow = (lane >> 4) * 4;
#pragma unroll
    for (int m = 0; m < 4; ++m) {
#pragma unroll
        for (int n = 0; n < 4; ++n) {
            const int col = n0 + wn + n * 16 + fr;
            const float bsum = bias[col];
#pragma unroll
            for (int r = 0; r < 4; ++r) {
                const int row = m0 + wm + m * 16 + orow + r;
                Z[(size_t)row * N + col] = acc[m][n][r] + bsum;
            }
        }
    }
}

// ---------------------------------------------------------------------------
// IndRNN scan (in-place fp32) + BN stats. One thread per (b,h).
// ---------------------------------------------------------------------------
__global__ __launch_bounds__(256) void scan_bn_stats(
    float* __restrict__ Z, const float* __restrict__ u,
    float* __restrict__ sum, float* __restrict__ sumsq)
{
    const int idx = blockIdx.x * blockDim.x + threadIdx.x;   // b*H + h
    const int h = idx & (H_ - 1);
    const float uu = u[h];
    float hprev = 0.f, s1 = 0.f, s2 = 0.f;
#pragma unroll 4
    for (int t = 0; t < T_; ++t) {
        const size_t off = (size_t)t * (B_ * H_) + idx;
        float z = Z[off];
        float hv = z + uu * hprev;
        hv = hv > 0.f ? hv : 0.f;
        Z[off] = hv;
        hprev = hv;
        s1 += hv;
        s2 += hv * hv;
    }
    atomicAdd(&sum[h], s1);
    atomicAdd(&sumsq[h], s2);
}

// ---------------------------------------------------------------------------
__global__ void bn_finalize(
    const float* __restrict__ sum, const float* __restrict__ sumsq,
    const float* __restrict__ gamma, const float* __restrict__ beta,
    float* __restrict__ scale, float* __restrict__ shift)
{
    const int h = blockIdx.x * blockDim.x + threadIdx.x;
    if (h >= H_) return;
    const float inv_n = 1.f / (float)(T_ * B_);
    const float m = sum[h] * inv_n;
    const float v = sumsq[h] * inv_n - m * m;
    const float s = gamma[h] * rsqrtf(v + BN_EPS);
    scale[h] = s;
    shift[h] = beta[h] - m * s;
}

// ---------------------------------------------------------------------------
// BN-apply + bf16 convert: Ab[i] = bf16(H[i]*scale[h] + shift[h]), 4 elems/thread
// ---------------------------------------------------------------------------
__global__ __launch_bounds__(256) void bn_apply_bf16(
    const float* __restrict__ Hraw, const float* __restrict__ scale,
    const float* __restrict__ shift, short* __restrict__ Ab)
{
    const size_t idx = (size_t)blockIdx.x * blockDim.x + threadIdx.x;
    const int h4 = (int)((idx * 4) & (H_ - 1));
    float4 v = *(const float4*)(Hraw + idx * 4);
    float4 sc = *(const float4*)(scale + h4);
    float4 sh = *(const float4*)(shift + h4);
    short4 s;
    s.x = f2bf(v.x * sc.x + sh.x);
    s.y = f2bf(v.y * sc.y + sh.y);
    s.z = f2bf(v.z * sc.z + sh.z);
    s.w = f2bf(v.w * sc.w + sh.w);
    *(short4*)(Ab + idx * 4) = s;
}

// ---------------------------------------------------------------------------
// fp32 [rows][K0REAL] -> bf16 [rows][K0PAD] zero-padded
// ---------------------------------------------------------------------------
__global__ __launch_bounds__(256) void conv_pad(
    const float* __restrict__ X, short* __restrict__ Xb, int rows)
{
    const int npr = K0PAD / 4;   // 40
    const int idx = blockIdx.x * blockDim.x + threadIdx.x;
    if (idx >= rows * npr) return;
    const int r = idx / npr;
    const int c4 = (idx - r * npr) * 4;
    short4 s = {0, 0, 0, 0};
    if (c4 < K0REAL) {
        float4 v = *(const float4*)(X + (size_t)r * K0REAL + c4);
        s.x = f2bf(v.x); s.y = f2bf(v.y); s.z = f2bf(v.z); s.w = f2bf(v.w);
    }
    *(short4*)(Xb + (size_t)r * K0PAD + c4) = s;
}

// ---------------------------------------------------------------------------
__global__ __launch_bounds__(256) void conv_bf16(
    const float* __restrict__ Wf, short* __restrict__ Wb, int n4)
{
    const int idx = blockIdx.x * blockDim.x + threadIdx.x;
    if (idx >= n4) return;
    float4 v = *(const float4*)(Wf + (size_t)idx * 4);
    short4 s;
    s.x = f2bf(v.x); s.y = f2bf(v.y); s.z = f2bf(v.z); s.w = f2bf(v.w);
    *(short4*)(Wb + (size_t)idx * 4) = s;
}

// ---------------------------------------------------------------------------
// out[b,c] = sum_h bn(Hlast[b,h]) * Wlast[c,h] + blast[c]; one wave per (b,c).
// ---------------------------------------------------------------------------
__global__ __launch_bounds__(256) void final_proj(
    const float* __restrict__ Hlast, const float* __restrict__ scale,
    const float* __restrict__ shift, const float* __restrict__ Wlast,
    const float* __restrict__ blast, float* __restrict__ out)
{
    const int wave = (blockIdx.x * blockDim.x + threadIdx.x) >> 6;
    const int lane = threadIdx.x & 63;
    if (wave >= B_ * C_) return;
    const int b = wave / C_;
    const int c = wave % C_;
    float acc = 0.f;
    for (int h = lane; h < H_; h += 64) {
        float hv = Hlast[(size_t)b * H_ + h] * scale[h] + shift[h];
        acc += hv * Wlast[(size_t)c * H_ + h];
    }
#pragma unroll
    for (int o = 32; o > 0; o >>= 1) acc += __shfl_down(acc, o);
    if (lane == 0) out[(size_t)b * C_ + c] = acc + blast[c];
}

// ---------------------------------------------------------------------------
extern "C" void kernel_launch(void* const* d_in, const int* in_sizes, int n_in,
                              void* d_out, int out_size, void* d_ws, size_t ws_size,
                              hipStream_t stream)
{
    const float* x      = (const float*)d_in[0];  // [8192,144]
    const float* W0     = (const float*)d_in[1];  // [2048,144]
    const float* Ws     = (const float*)d_in[2];  // [3,2048,2048]
    const float* bs     = (const float*)d_in[3];  // [4,2048]
    const float* us     = (const float*)d_in[4];
    const float* gammas = (const float*)d_in[5];
    const float* betas  = (const float*)d_in[6];
    const float* Wlast  = (const float*)d_in[7];  // [10,2048]
    const float* blast  = (const float*)d_in[8];
    float* out = (float*)d_out;

    char* ws = (char*)d_ws;
    float* buf0    = (float*)ws;                            // 64 MB fp32 work
    short* Ab      = (short*)(ws + (size_t)64  * 1048576);  // 32 MB bf16 acts
    short* Wb      = (short*)(ws + (size_t)96  * 1048576);  // 24 MB bf16 weights
    short* X0b     = (short*)(ws + (size_t)120 * 1048576);  // 2.56 MB
    short* W0b     = (short*)(ws + (size_t)123 * 1048576);  // 0.64 MB
    float* sum     = (float*)(ws + (size_t)124 * 1048576);
    float* sumsq   = sum + H_;
    float* bnscale = sumsq + H_;
    float* bnshift = bnscale + H_;

    const int M = T_ * B_;                      // 8192
    const dim3 gemm_grid(H_ / 128, M / 128);    // (16, 64) = 1024 blocks

    // one-time (per launch) conversions
    conv_pad<<<(M * (K0PAD / 4) + 255) / 256, 256, 0, stream>>>(x, X0b, M);
    conv_pad<<<(H_ * (K0PAD / 4) + 255) / 256, 256, 0, stream>>>(W0, W0b, H_);
    conv_bf16<<<(3 * H_ * H_ / 4 + 255) / 256, 256, 0, stream>>>(Ws, Wb, 3 * H_ * H_ / 4);

    // layer 0 projection (K padded to 160)
    gemm_bf16_lds<<<gemm_grid, 256, 0, stream>>>(X0b, W0b, bs, buf0, M, H_, K0PAD);

    for (int l = 0; l < L_; ++l) {
        hipMemsetAsync(sum, 0, 2 * H_ * sizeof(float), stream);
        scan_bn_stats<<<(B_ * H_) / 256, 256, 0, stream>>>(buf0, us + l * H_, sum, sumsq);
        bn_finalize<<<H_ / 256, 256, 0, stream>>>(sum, sumsq,
                                                  gammas + l * H_, betas + l * H_,
                                                  bnscale, bnshift);
        if (l < L_ - 1) {
            bn_apply_bf16<<<(T_ * B_ * H_ / 4) / 256, 256, 0, stream>>>(
                buf0, bnscale, bnshift, Ab);
            gemm_bf16_lds<<<gemm_grid, 256, 0, stream>>>(
                Ab, Wb + (size_t)l * H_ * H_, bs + (l + 1) * H_, buf0, M, H_, H_);
        }
    }

    final_proj<<<(B_ * C_ * 64 + 255) / 256, 256, 0, stream>>>(
        buf0 + (size_t)(T_ - 1) * B_ * H_, bnscale, bnshift, Wlast, blast, out);
}

// Round 4
// 475.354 us; speedup vs baseline: 2.5973x; 1.2622x over previous
//
#include <hip/hip_runtime.h>

#define T_    128
#define B_    64
#define H_    2048
#define L_    4
#define C_    10
#define BN_EPS 1e-5f
#define K0REAL 144
#define K0PAD  160

typedef __attribute__((ext_vector_type(8))) short bf16x8;
typedef __attribute__((ext_vector_type(4))) float f32x4;

__device__ __forceinline__ short f2bf(float f) {
    union { float f; unsigned u; } v; v.f = f;
    unsigned r = (v.u + 0x7FFFu + ((v.u >> 16) & 1u)) >> 16;
    return (short)r;
}
__device__ __forceinline__ float bf2f(short s) {
    union { unsigned u; float f; } v; v.u = ((unsigned)(unsigned short)s) << 16;
    return v.f;
}
__device__ __forceinline__ void gload16(const short* g, short* l) {
    __builtin_amdgcn_global_load_lds(
        (const __attribute__((address_space(1))) void*)g,
        (__attribute__((address_space(3))) void*)l, 16, 0, 0);
}

#define SBAR() do { __builtin_amdgcn_sched_barrier(0); \
                    __builtin_amdgcn_s_barrier();      \
                    __builtin_amdgcn_sched_barrier(0); } while (0)

// ---------------------------------------------------------------------------
// 256x256 tile, BK=32, 512 threads = 8 waves (2M x 4N), pipelined with
// counted vmcnt (T3+T4), read-side XOR swizzle (T2), setprio (T5).
// Requires: grid = (M/256, N/256) with N/256 == 8, Kb % 64 == 0.
// LDS: 2 bufs x 2 halves x [128 rows][32 cols] bf16 per operand = 64 KB.
// ---------------------------------------------------------------------------
__global__ __launch_bounds__(512, 2) void gemm_bf16_256(
    const short* __restrict__ A, const short* __restrict__ Bw,
    const float* __restrict__ bias, float* __restrict__ Z,
    int M, int N, int Kb)
{
    __shared__ short As[2][2][128 * 32];
    __shared__ short Bs[2][2][128 * 32];

    const int tid  = threadIdx.x;
    const int wid  = tid >> 6;          // 0..7
    const int lane = tid & 63;

    // XCD-aware mapping: original linear id i -> XCD i%8 -> n-panel (i&7).
    const int lin = blockIdx.y * gridDim.x + blockIdx.x;
    const int m0  = (lin >> 3) * 256;
    const int n0  = (lin & 7) * 256;

    // wave tile: 2 wave-rows x 4 wave-cols; per wave 128 rows x 64 cols
    const int wm  = (wid >> 2) * 128;
    const int wn  = (wid & 3) * 64;
    const int ha  = wid >> 2;           // A half this wave reads
    const int hb  = wn >> 7;            // B half this wave reads
    const int lrB = wn & 127;           // B row base within half

    const int fr  = lane & 15;
    const int fq  = lane >> 4;          // 0..3
    // read-side swizzle: 16B slot = fq ^ (lds_row & 3); row&3 == fr&3 here
    const int rds = ((fq ^ (fr & 3)) * 8);     // short offset within row

    // staging map (per gload_lds: 64 lanes x 16B = 16 rows x 64B)
    const int s_row = wid * 16 + (lane >> 2);           // row within 128-half
    const int s_col = (((lane & 3) ^ ((lane >> 2) & 3)) * 8); // swizzled src col
    const int s_dst = wid * 16 * 32 + lane * 8;         // linear LDS dest (shorts)

    auto stageA = [&](int kt, int half) {
        gload16(A + (size_t)(m0 + half * 128 + s_row) * Kb + kt * 32 + s_col,
                &As[kt & 1][half][s_dst]);
    };
    auto stageB = [&](int kt, int half) {
        gload16(Bw + (size_t)(n0 + half * 128 + s_row) * Kb + kt * 32 + s_col,
                &Bs[kt & 1][half][s_dst]);
    };

    f32x4 acc[8][4];
#pragma unroll
    for (int m = 0; m < 8; ++m)
#pragma unroll
        for (int n = 0; n < 4; ++n)
            acc[m][n] = (f32x4){0.f, 0.f, 0.f, 0.f};

    const int NK = Kb >> 5;

    // ---- prologue: kt0 fully + kt1 B; wait kt0 landed (allow kt1 B in flight)
    stageB(0, 0); stageB(0, 1);
    stageA(0, 0); stageA(0, 1);
    if (NK > 1) { stageB(1, 0); stageB(1, 1); }
    asm volatile("s_waitcnt vmcnt(2)" ::: "memory");
    SBAR();

    bf16x8 bfrag[4], afrag[4];

#pragma unroll 1
    for (int g = 0; g < NK; ++g) {
        const int buf = g & 1;
        // ---------- phase A: frag reads (B all + A m0..3), stage (g+1)A ----
#pragma unroll
        for (int n = 0; n < 4; ++n)
            bfrag[n] = *(const bf16x8*)&Bs[buf][hb][(lrB + n * 16 + fr) * 32 + rds];
#pragma unroll
        for (int m = 0; m < 4; ++m)
            afrag[m] = *(const bf16x8*)&As[buf][ha][(m * 16 + fr) * 32 + rds];
        if (g + 1 < NK) { stageA(g + 1, 0); stageA(g + 1, 1); }
        SBAR();
        __builtin_amdgcn_s_setprio(1);
#pragma unroll
        for (int m = 0; m < 4; ++m)
#pragma unroll
            for (int n = 0; n < 4; ++n)
                acc[m][n] = __builtin_amdgcn_mfma_f32_16x16x32_bf16(
                    afrag[m], bfrag[n], acc[m][n], 0, 0, 0);
        __builtin_amdgcn_s_setprio(0);
        SBAR();
        // ---------- phase B: frag reads (A m4..7), stage (g+2)B -------------
#pragma unroll
        for (int m = 0; m < 4; ++m)
            afrag[m] = *(const bf16x8*)&As[buf][ha][((m + 4) * 16 + fr) * 32 + rds];
        if (g + 2 < NK) { stageB(g + 2, 0); stageB(g + 2, 1); }
        SBAR();
        __builtin_amdgcn_s_setprio(1);
#pragma unroll
        for (int m = 0; m < 4; ++m)
#pragma unroll
            for (int n = 0; n < 4; ++n)
                acc[m + 4][n] = __builtin_amdgcn_mfma_f32_16x16x32_bf16(
                    afrag[m], bfrag[n], acc[m + 4][n], 0, 0, 0);
        __builtin_amdgcn_s_setprio(0);
        // counted vmcnt once per K-tile: (g+1)A must land; allow (g+2)B in flight
        asm volatile("s_waitcnt vmcnt(2)" ::: "memory");
        SBAR();
    }

    // ---- epilogue: D map col=lane&15, row=(lane>>4)*4+r -------------------
#pragma unroll
    for (int m = 0; m < 8; ++m) {
#pragma unroll
        for (int n = 0; n < 4; ++n) {
            const int col = n0 + wn + n * 16 + fr;
            const float bsum = bias[col];
#pragma unroll
            for (int r = 0; r < 4; ++r) {
                const int row = m0 + wm + m * 16 + fq * 4 + r;
                Z[(size_t)row * N + col] = acc[m][n][r] + bsum;
            }
        }
    }
}

// ---------------------------------------------------------------------------
// 128x128 / BK=32 GEMM (round-3, verified) — used for the K=160 layer-0 GEMM.
// ---------------------------------------------------------------------------
__global__ __launch_bounds__(256) void gemm_bf16_lds(
    const short* __restrict__ A, const short* __restrict__ Bw,
    const float* __restrict__ bias,
    float* __restrict__ Z, int M, int N, int Kb)
{
    __shared__ short As[128 * 32];
    __shared__ short Bs[128 * 32];

    const int tid = threadIdx.x;
    const int nwg = gridDim.x * gridDim.y;
    int lin = blockIdx.y * gridDim.x + blockIdx.x;
    lin = (lin & 7) * (nwg >> 3) + (lin >> 3);
    const int bx = lin % gridDim.x;
    const int by = lin / gridDim.x;
    const int m0 = by * 128;
    const int n0 = bx * 128;

    const int srow = tid >> 2;
    const int scol = (tid & 3) * 8;

    const int wid  = tid >> 6;
    const int lane = tid & 63;
    const int wm   = (wid >> 1) * 64;
    const int wn   = (wid & 1) * 64;
    const int fr   = lane & 15;
    const int fk   = (lane >> 4) * 8;

    f32x4 acc[4][4];
#pragma unroll
    for (int m = 0; m < 4; ++m)
#pragma unroll
        for (int n = 0; n < 4; ++n)
            acc[m][n] = (f32x4){0.f, 0.f, 0.f, 0.f};

    const short* Abase = A + (size_t)m0 * Kb;
    const short* Bbase = Bw + (size_t)n0 * Kb;

    for (int k0 = 0; k0 < Kb; k0 += 32) {
        gload16(Abase + (size_t)srow        * Kb + k0 + scol, &As[tid * 8]);
        gload16(Abase + (size_t)(srow + 64) * Kb + k0 + scol, &As[2048 + tid * 8]);
        gload16(Bbase + (size_t)srow        * Kb + k0 + scol, &Bs[tid * 8]);
        gload16(Bbase + (size_t)(srow + 64) * Kb + k0 + scol, &Bs[2048 + tid * 8]);
        __syncthreads();

        bf16x8 af[4], bfv[4];
#pragma unroll
        for (int m = 0; m < 4; ++m)
            af[m] = *(const bf16x8*)&As[(wm + m * 16 + fr) * 32 + fk];
#pragma unroll
        for (int n = 0; n < 4; ++n)
            bfv[n] = *(const bf16x8*)&Bs[(wn + n * 16 + fr) * 32 + fk];

#pragma unroll
        for (int m = 0; m < 4; ++m)
#pragma unroll
            for (int n = 0; n < 4; ++n)
                acc[m][n] = __builtin_amdgcn_mfma_f32_16x16x32_bf16(
                    af[m], bfv[n], acc[m][n], 0, 0, 0);
        __syncthreads();
    }

    const int orow = (lane >> 4) * 4;
#pragma unroll
    for (int m = 0; m < 4; ++m) {
#pragma unroll
        for (int n = 0; n < 4; ++n) {
            const int col = n0 + wn + n * 16 + fr;
            const float bsum = bias[col];
#pragma unroll
            for (int r = 0; r < 4; ++r) {
                const int row = m0 + wm + m * 16 + orow + r;
                Z[(size_t)row * N + col] = acc[m][n][r] + bsum;
            }
        }
    }
}

// ---------------------------------------------------------------------------
// IndRNN scan: read z (fp32), recurrence in fp32, write h as bf16 + BN stats.
// ---------------------------------------------------------------------------
__global__ __launch_bounds__(256) void scan_bf16(
    const float* __restrict__ Z, const float* __restrict__ u,
    short* __restrict__ Hb, float* __restrict__ sum, float* __restrict__ sumsq)
{
    const int idx = blockIdx.x * blockDim.x + threadIdx.x;   // b*H + h
    const int h = idx & (H_ - 1);
    const float uu = u[h];
    float hprev = 0.f, s1 = 0.f, s2 = 0.f;
#pragma unroll 4
    for (int t = 0; t < T_; ++t) {
        const size_t off = (size_t)t * (B_ * H_) + idx;
        float z = Z[off];
        float hv = z + uu * hprev;
        hv = hv > 0.f ? hv : 0.f;
        Hb[off] = f2bf(hv);
        hprev = hv;
        s1 += hv;
        s2 += hv * hv;
    }
    atomicAdd(&sum[h], s1);
    atomicAdd(&sumsq[h], s2);
}

// ---------------------------------------------------------------------------
__global__ void bn_finalize(
    const float* __restrict__ sum, const float* __restrict__ sumsq,
    const float* __restrict__ gamma, const float* __restrict__ beta,
    float* __restrict__ scale, float* __restrict__ shift)
{
    const int h = blockIdx.x * blockDim.x + threadIdx.x;
    if (h >= H_) return;
    const float inv_n = 1.f / (float)(T_ * B_);
    const float m = sum[h] * inv_n;
    const float v = sumsq[h] * inv_n - m * m;
    const float s = gamma[h] * rsqrtf(v + BN_EPS);
    scale[h] = s;
    shift[h] = beta[h] - m * s;
}

// ---------------------------------------------------------------------------
// Fold BN into weights: W'[n,k] = bf16(W[n,k] * scale[k])
// ---------------------------------------------------------------------------
__global__ __launch_bounds__(256) void fold_weights(
    const float* __restrict__ Wf, const float* __restrict__ scale,
    short* __restrict__ Wb)
{
    const size_t idx = (size_t)blockIdx.x * blockDim.x + threadIdx.x;
    const int k4 = (int)((idx * 4) & (H_ - 1));
    float4 w = *(const float4*)(Wf + idx * 4);
    float4 sc = *(const float4*)(scale + k4);
    short4 s;
    s.x = f2bf(w.x * sc.x); s.y = f2bf(w.y * sc.y);
    s.z = f2bf(w.z * sc.z); s.w = f2bf(w.w * sc.w);
    *(short4*)(Wb + idx * 4) = s;
}

// ---------------------------------------------------------------------------
// bias'[n] = b[n] + sum_k shift[k] * W[n,k]   (one wave per n)
// ---------------------------------------------------------------------------
__global__ __launch_bounds__(256) void fold_bias(
    const float* __restrict__ Wf, const float* __restrict__ shift,
    const float* __restrict__ b, float* __restrict__ bias2)
{
    const int wave = (blockIdx.x * blockDim.x + threadIdx.x) >> 6;
    const int lane = threadIdx.x & 63;
    if (wave >= H_) return;
    float acc = 0.f;
    for (int k = lane; k < H_; k += 64)
        acc += shift[k] * Wf[(size_t)wave * H_ + k];
#pragma unroll
    for (int o = 32; o > 0; o >>= 1) acc += __shfl_down(acc, o);
    if (lane == 0) bias2[wave] = acc + b[wave];
}

// ---------------------------------------------------------------------------
// fp32 [rows][K0REAL] -> bf16 [rows][K0PAD] zero-padded
// ---------------------------------------------------------------------------
__global__ __launch_bounds__(256) void conv_pad(
    const float* __restrict__ X, short* __restrict__ Xb, int rows)
{
    const int npr = K0PAD / 4;   // 40
    const int idx = blockIdx.x * blockDim.x + threadIdx.x;
    if (idx >= rows * npr) return;
    const int r = idx / npr;
    const int c4 = (idx - r * npr) * 4;
    short4 s = {0, 0, 0, 0};
    if (c4 < K0REAL) {
        float4 v = *(const float4*)(X + (size_t)r * K0REAL + c4);
        s.x = f2bf(v.x); s.y = f2bf(v.y); s.z = f2bf(v.z); s.w = f2bf(v.w);
    }
    *(short4*)(Xb + (size_t)r * K0PAD + c4) = s;
}

// ---------------------------------------------------------------------------
// out[b,c] = sum_h (bf2f(Hb[b,h])*scale[h]+shift[h]) * Wlast[c,h] + blast[c]
// ---------------------------------------------------------------------------
__global__ __launch_bounds__(256) void final_proj(
    const short* __restrict__ Hb, const float* __restrict__ scale,
    const float* __restrict__ shift, const float* __restrict__ Wlast,
    const float* __restrict__ blast, float* __restrict__ out)
{
    const int wave = (blockIdx.x * blockDim.x + threadIdx.x) >> 6;
    const int lane = threadIdx.x & 63;
    if (wave >= B_ * C_) return;
    const int b = wave / C_;
    const int c = wave % C_;
    float acc = 0.f;
    for (int h = lane; h < H_; h += 64) {
        float hv = bf2f(Hb[(size_t)b * H_ + h]) * scale[h] + shift[h];
        acc += hv * Wlast[(size_t)c * H_ + h];
    }
#pragma unroll
    for (int o = 32; o > 0; o >>= 1) acc += __shfl_down(acc, o);
    if (lane == 0) out[(size_t)b * C_ + c] = acc + blast[c];
}

// ---------------------------------------------------------------------------
extern "C" void kernel_launch(void* const* d_in, const int* in_sizes, int n_in,
                              void* d_out, int out_size, void* d_ws, size_t ws_size,
                              hipStream_t stream)
{
    const float* x      = (const float*)d_in[0];  // [8192,144]
    const float* W0     = (const float*)d_in[1];  // [2048,144]
    const float* Ws     = (const float*)d_in[2];  // [3,2048,2048]
    const float* bs     = (const float*)d_in[3];  // [4,2048]
    const float* us     = (const float*)d_in[4];
    const float* gammas = (const float*)d_in[5];
    const float* betas  = (const float*)d_in[6];
    const float* Wlast  = (const float*)d_in[7];  // [10,2048]
    const float* blast  = (const float*)d_in[8];
    float* out = (float*)d_out;

    char* ws = (char*)d_ws;
    float* buf0    = (float*)ws;                            // 64 MB fp32 z
    short* Ab      = (short*)(ws + (size_t)64  * 1048576);  // 32 MB bf16 h
    short* Wb      = (short*)(ws + (size_t)96  * 1048576);  // 8 MB folded W
    short* X0b     = (short*)(ws + (size_t)104 * 1048576);  // 2.56 MB
    short* W0b     = (short*)(ws + (size_t)107 * 1048576);  // 0.64 MB
    float* sum     = (float*)(ws + (size_t)108 * 1048576);
    float* sumsq   = sum + H_;
    float* bnscale = sumsq + H_;
    float* bnshift = bnscale + H_;
    float* bias2   = bnshift + H_;

    const int M = T_ * B_;   // 8192

    conv_pad<<<(M * (K0PAD / 4) + 255) / 256, 256, 0, stream>>>(x, X0b, M);
    conv_pad<<<(H_ * (K0PAD / 4) + 255) / 256, 256, 0, stream>>>(W0, W0b, H_);

    // layer 0 projection (K padded to 160): proven 128^2 kernel
    gemm_bf16_lds<<<dim3(H_ / 128, M / 128), 256, 0, stream>>>(
        X0b, W0b, bs, buf0, M, H_, K0PAD);

    const dim3 g256(M / 256, H_ / 256);   // (32, 8) = 256 blocks
    for (int l = 0; l < L_; ++l) {
        hipMemsetAsync(sum, 0, 2 * H_ * sizeof(float), stream);
        scan_bf16<<<(B_ * H_) / 256, 256, 0, stream>>>(buf0, us + l * H_, Ab, sum, sumsq);
        bn_finalize<<<H_ / 256, 256, 0, stream>>>(sum, sumsq,
                                                  gammas + l * H_, betas + l * H_,
                                                  bnscale, bnshift);
        if (l < L_ - 1) {
            const float* Wl = Ws + (size_t)l * H_ * H_;
            fold_weights<<<(H_ * H_ / 4) / 256, 256, 0, stream>>>(Wl, bnscale, Wb);
            fold_bias<<<(H_ * 64) / 256, 256, 0, stream>>>(Wl, bnshift,
                                                           bs + (l + 1) * H_, bias2);
            gemm_bf16_256<<<g256, 512, 0, stream>>>(Ab, Wb, bias2, buf0, M, H_, H_);
        }
    }

    final_proj<<<(B_ * C_ * 64 + 255) / 256, 256, 0, stream>>>(
        Ab + (size_t)(T_ - 1) * B_ * H_, bnscale, bnshift, Wlast, blast, out);
}

// Round 5
// 445.878 us; speedup vs baseline: 2.7690x; 1.0661x over previous
//
#include <hip/hip_runtime.h>

#define T_    128
#define B_    64
#define H_    2048
#define L_    4
#define C_    10
#define BN_EPS 1e-5f
#define K0REAL 144
#define K0PAD  160

typedef __attribute__((ext_vector_type(8))) short bf16x8;
typedef __attribute__((ext_vector_type(4))) float f32x4;

__device__ __forceinline__ short f2bf(float f) {
    union { float f; unsigned u; } v; v.f = f;
    unsigned r = (v.u + 0x7FFFu + ((v.u >> 16) & 1u)) >> 16;
    return (short)r;
}
__device__ __forceinline__ float bf2f(short s) {
    union { unsigned u; float f; } v; v.u = ((unsigned)(unsigned short)s) << 16;
    return v.f;
}
__device__ __forceinline__ void gload16(const short* g, short* l) {
    __builtin_amdgcn_global_load_lds(
        (const __attribute__((address_space(1))) void*)g,
        (__attribute__((address_space(3))) void*)l, 16, 0, 0);
}

#define SBAR() do { __builtin_amdgcn_sched_barrier(0); \
                    __builtin_amdgcn_s_barrier();      \
                    __builtin_amdgcn_sched_barrier(0); } while (0)

// ---------------------------------------------------------------------------
// m201-style 256x256 / BK=64 / 8-wave pipelined GEMM.
// Z[M,N] = A[M,Kb] @ Bw[N,Kb]^T + bias  (bf16 in, fp32 out)
// 4 phases per K-tile, 16 MFMA each; full XOR slot swizzle (T2); counted
// vmcnt(8) once per K-tile (T4); setprio around MFMA (T5).
// Grid must be (M/256, N/256) with N/256 == 8; Kb % 64 == 0, Kb/64 >= 2.
// ---------------------------------------------------------------------------
__global__ __launch_bounds__(512, 2) void gemm_bf16_8ph(
    const short* __restrict__ A, const short* __restrict__ Bw,
    const float* __restrict__ bias, float* __restrict__ Z,
    int M, int N, int Kb)
{
    // per operand: 2 bufs x 256 rows x 64 cols bf16 = 64 KB (128 KB total)
    __shared__ short As[2][256 * 64];
    __shared__ short Bs[2][256 * 64];

    const int tid  = threadIdx.x;
    const int wid  = tid >> 6;
    const int lane = tid & 63;

    // n-panel == XCD id (linear block id % 8 round-robins XCDs)
    const int lin = blockIdx.y * gridDim.x + blockIdx.x;
    const int m0  = (lin >> 3) * 256;
    const int n0  = (lin & 7) * 256;

    // wave tile: 2M x 4N waves; per wave 128 rows x 64 cols
    const int wm  = (wid >> 2) * 128;
    const int wn  = (wid & 3) * 64;

    const int fr  = lane & 15;
    const int fq  = lane >> 4;
    const int fr7 = fr & 7;

    // staging map: wave w, load i in {0,1}, half h -> 8 rows x 8 slots
    const int s_sub   = wid * 2;
    const int s_rowi  = lane >> 3;             // 0..7
    const int s_chunk = (lane & 7) ^ s_rowi;   // pre-swizzled global col chunk

    auto stA = [&](int kt, int h, int i) {
        const int r = h * 128 + (s_sub + i) * 8 + s_rowi;
        gload16(A + (size_t)(m0 + r) * Kb + kt * 64 + s_chunk * 8,
                &As[kt & 1][h * 8192 + (s_sub + i) * 512 + lane * 8]);
    };
    auto stB = [&](int kt, int h, int i) {
        const int r = h * 128 + (s_sub + i) * 8 + s_rowi;
        gload16(Bw + (size_t)(n0 + r) * Kb + kt * 64 + s_chunk * 8,
                &Bs[kt & 1][h * 8192 + (s_sub + i) * 512 + lane * 8]);
    };
    // swizzled fragment reads: slot = (kk*4+fq) ^ (row&7), row&7 == fr&7
    auto rdA = [&](int buf, int m, int kk) -> bf16x8 {
        const int ar = wm + m * 16 + fr;
        const int slot = (kk * 4 + fq) ^ fr7;
        return *(const bf16x8*)&As[buf][ar * 64 + slot * 8];
    };
    auto rdB = [&](int buf, int n, int kk) -> bf16x8 {
        const int br = wn + n * 16 + fr;
        const int slot = (kk * 4 + fq) ^ fr7;
        return *(const bf16x8*)&Bs[buf][br * 64 + slot * 8];
    };

    f32x4 acc[8][4];
#pragma unroll
    for (int m = 0; m < 8; ++m)
#pragma unroll
        for (int n = 0; n < 4; ++n)
            acc[m][n] = (f32x4){0.f, 0.f, 0.f, 0.f};

    const int NK = Kb >> 6;

    // ---- prologue: stage tile 0 and tile 1; wait tile 0 (8 of 16 left) ----
    stA(0, 0, 0); stA(0, 0, 1); stA(0, 1, 0); stA(0, 1, 1);
    stB(0, 0, 0); stB(0, 0, 1); stB(0, 1, 0); stB(0, 1, 1);
    stA(1, 0, 0); stA(1, 0, 1); stA(1, 1, 0); stA(1, 1, 1);
    stB(1, 0, 0); stB(1, 0, 1); stB(1, 1, 0); stB(1, 1, 1);
    asm volatile("s_waitcnt vmcnt(8)" ::: "memory");
    SBAR();

    bf16x8 aF[4][2], b0[2][2], b1[2][2];

#pragma unroll 1
    for (int g = 0; g < NK; ++g) {
        const int buf = g & 1;
        // ---- P1: read A m0-3 (8) + B n0-1 (4); MFMA q(m0-3, n0-1) --------
#pragma unroll
        for (int m = 0; m < 4; ++m)
#pragma unroll
            for (int kk = 0; kk < 2; ++kk) aF[m][kk] = rdA(buf, m, kk);
#pragma unroll
        for (int n = 0; n < 2; ++n)
#pragma unroll
            for (int kk = 0; kk < 2; ++kk) b0[n][kk] = rdB(buf, n, kk);
        SBAR();
        __builtin_amdgcn_s_setprio(1);
#pragma unroll
        for (int m = 0; m < 4; ++m)
#pragma unroll
            for (int n = 0; n < 2; ++n)
#pragma unroll
                for (int kk = 0; kk < 2; ++kk)
                    acc[m][n] = __builtin_amdgcn_mfma_f32_16x16x32_bf16(
                        aF[m][kk], b0[n][kk], acc[m][n], 0, 0, 0);
        __builtin_amdgcn_s_setprio(0);
        SBAR();
        // ---- P2: read B n2-3 (4); MFMA q(m0-3, n2-3) ---------------------
#pragma unroll
        for (int n = 0; n < 2; ++n)
#pragma unroll
            for (int kk = 0; kk < 2; ++kk) b1[n][kk] = rdB(buf, n + 2, kk);
        SBAR();
        __builtin_amdgcn_s_setprio(1);
#pragma unroll
        for (int m = 0; m < 4; ++m)
#pragma unroll
            for (int n = 0; n < 2; ++n)
#pragma unroll
                for (int kk = 0; kk < 2; ++kk)
                    acc[m][n + 2] = __builtin_amdgcn_mfma_f32_16x16x32_bf16(
                        aF[m][kk], b1[n][kk], acc[m][n + 2], 0, 0, 0);
        __builtin_amdgcn_s_setprio(0);
        SBAR();
        // ---- P3: read A m4-7 (8, reuse aF regs); stage B(g+2);
        //          MFMA q(m4-7, n2-3)  [B fully read after P2 barrier] -----
#pragma unroll
        for (int m = 0; m < 4; ++m)
#pragma unroll
            for (int kk = 0; kk < 2; ++kk) aF[m][kk] = rdA(buf, m + 4, kk);
        if (g + 2 < NK) { stB(g + 2, 0, 0); stB(g + 2, 0, 1);
                          stB(g + 2, 1, 0); stB(g + 2, 1, 1); }
        SBAR();
        __builtin_amdgcn_s_setprio(1);
#pragma unroll
        for (int m = 0; m < 4; ++m)
#pragma unroll
            for (int n = 0; n < 2; ++n)
#pragma unroll
                for (int kk = 0; kk < 2; ++kk)
                    acc[m + 4][n + 2] = __builtin_amdgcn_mfma_f32_16x16x32_bf16(
                        aF[m][kk], b1[n][kk], acc[m + 4][n + 2], 0, 0, 0);
        __builtin_amdgcn_s_setprio(0);
        SBAR();
        // ---- P4: stage A(g+2) [A fully read after P3 barrier];
        //          MFMA q(m4-7, n0-1); counted vmcnt -----------------------
        if (g + 2 < NK) { stA(g + 2, 0, 0); stA(g + 2, 0, 1);
                          stA(g + 2, 1, 0); stA(g + 2, 1, 1); }
        __builtin_amdgcn_s_setprio(1);
#pragma unroll
        for (int m = 0; m < 4; ++m)
#pragma unroll
            for (int n = 0; n < 2; ++n)
#pragma unroll
                for (int kk = 0; kk < 2; ++kk)
                    acc[m + 4][n] = __builtin_amdgcn_mfma_f32_16x16x32_bf16(
                        aF[m][kk], b0[n][kk], acc[m + 4][n], 0, 0, 0);
        __builtin_amdgcn_s_setprio(0);
        if (g + 2 < NK) asm volatile("s_waitcnt vmcnt(8)" ::: "memory");
        else            asm volatile("s_waitcnt vmcnt(0)" ::: "memory");
        SBAR();
    }

    // ---- epilogue: D map col=lane&15, row=(lane>>4)*4+r -------------------
#pragma unroll
    for (int m = 0; m < 8; ++m) {
#pragma unroll
        for (int n = 0; n < 4; ++n) {
            const int col = n0 + wn + n * 16 + fr;
            const float bsum = bias[col];
#pragma unroll
            for (int r = 0; r < 4; ++r) {
                const int row = m0 + wm + m * 16 + fq * 4 + r;
                Z[(size_t)row * N + col] = acc[m][n][r] + bsum;
            }
        }
    }
}

// ---------------------------------------------------------------------------
// 128x128 / BK=32 GEMM (round-3, verified) — layer-0 (K=160) only.
// ---------------------------------------------------------------------------
__global__ __launch_bounds__(256) void gemm_bf16_lds(
    const short* __restrict__ A, const short* __restrict__ Bw,
    const float* __restrict__ bias,
    float* __restrict__ Z, int M, int N, int Kb)
{
    __shared__ short As[128 * 32];
    __shared__ short Bs[128 * 32];

    const int tid = threadIdx.x;
    const int nwg = gridDim.x * gridDim.y;
    int lin = blockIdx.y * gridDim.x + blockIdx.x;
    lin = (lin & 7) * (nwg >> 3) + (lin >> 3);
    const int bx = lin % gridDim.x;
    const int by = lin / gridDim.x;
    const int m0 = by * 128;
    const int n0 = bx * 128;

    const int srow = tid >> 2;
    const int scol = (tid & 3) * 8;

    const int wid  = tid >> 6;
    const int lane = tid & 63;
    const int wm   = (wid >> 1) * 64;
    const int wn   = (wid & 1) * 64;
    const int fr   = lane & 15;
    const int fk   = (lane >> 4) * 8;

    f32x4 acc[4][4];
#pragma unroll
    for (int m = 0; m < 4; ++m)
#pragma unroll
        for (int n = 0; n < 4; ++n)
            acc[m][n] = (f32x4){0.f, 0.f, 0.f, 0.f};

    const short* Abase = A + (size_t)m0 * Kb;
    const short* Bbase = Bw + (size_t)n0 * Kb;

    for (int k0 = 0; k0 < Kb; k0 += 32) {
        gload16(Abase + (size_t)srow        * Kb + k0 + scol, &As[tid * 8]);
        gload16(Abase + (size_t)(srow + 64) * Kb + k0 + scol, &As[2048 + tid * 8]);
        gload16(Bbase + (size_t)srow        * Kb + k0 + scol, &Bs[tid * 8]);
        gload16(Bbase + (size_t)(srow + 64) * Kb + k0 + scol, &Bs[2048 + tid * 8]);
        __syncthreads();

        bf16x8 af[4], bfv[4];
#pragma unroll
        for (int m = 0; m < 4; ++m)
            af[m] = *(const bf16x8*)&As[(wm + m * 16 + fr) * 32 + fk];
#pragma unroll
        for (int n = 0; n < 4; ++n)
            bfv[n] = *(const bf16x8*)&Bs[(wn + n * 16 + fr) * 32 + fk];

#pragma unroll
        for (int m = 0; m < 4; ++m)
#pragma unroll
            for (int n = 0; n < 4; ++n)
                acc[m][n] = __builtin_amdgcn_mfma_f32_16x16x32_bf16(
                    af[m], bfv[n], acc[m][n], 0, 0, 0);
        __syncthreads();
    }

    const int orow = (lane >> 4) * 4;
#pragma unroll
    for (int m = 0; m < 4; ++m) {
#pragma unroll
        for (int n = 0; n < 4; ++n) {
            const int col = n0 + wn + n * 16 + fr;
            const float bsum = bias[col];
#pragma unroll
            for (int r = 0; r < 4; ++r) {
                const int row = m0 + wm + m * 16 + orow + r;
                Z[(size_t)row * N + col] = acc[m][n][r] + bsum;
            }
        }
    }
}

// ---------------------------------------------------------------------------
// IndRNN scan: read z (fp32), recurrence fp32, write h bf16 + BN stats.
// ---------------------------------------------------------------------------
__global__ __launch_bounds__(256) void scan_bf16(
    const float* __restrict__ Z, const float* __restrict__ u,
    short* __restrict__ Hb, float* __restrict__ sum, float* __restrict__ sumsq)
{
    const int idx = blockIdx.x * blockDim.x + threadIdx.x;   // b*H + h
    const int h = idx & (H_ - 1);
    const float uu = u[h];
    float hprev = 0.f, s1 = 0.f, s2 = 0.f;
#pragma unroll 4
    for (int t = 0; t < T_; ++t) {
        const size_t off = (size_t)t * (B_ * H_) + idx;
        float z = Z[off];
        float hv = z + uu * hprev;
        hv = hv > 0.f ? hv : 0.f;
        Hb[off] = f2bf(hv);
        hprev = hv;
        s1 += hv;
        s2 += hv * hv;
    }
    atomicAdd(&sum[h], s1);
    atomicAdd(&sumsq[h], s2);
}

// ---------------------------------------------------------------------------
__global__ void bn_finalize(
    const float* __restrict__ sum, const float* __restrict__ sumsq,
    const float* __restrict__ gamma, const float* __restrict__ beta,
    float* __restrict__ scale, float* __restrict__ shift)
{
    const int h = blockIdx.x * blockDim.x + threadIdx.x;
    if (h >= H_) return;
    const float inv_n = 1.f / (float)(T_ * B_);
    const float m = sum[h] * inv_n;
    const float v = sumsq[h] * inv_n - m * m;
    const float s = gamma[h] * rsqrtf(v + BN_EPS);
    scale[h] = s;
    shift[h] = beta[h] - m * s;
}

// ---------------------------------------------------------------------------
// Fused BN fold: Wb[n,k] = bf16(W[n,k]*scale[k]);
//                bias2[n] = b[n] + sum_k shift[k]*W[n,k].  One wave per row.
// ---------------------------------------------------------------------------
__global__ __launch_bounds__(256) void fold_wb(
    const float* __restrict__ Wf, const float* __restrict__ scale,
    const float* __restrict__ shift, const float* __restrict__ b,
    short* __restrict__ Wb, float* __restrict__ bias2)
{
    const int wrow = (blockIdx.x * blockDim.x + threadIdx.x) >> 6;
    const int lane = threadIdx.x & 63;
    if (wrow >= H_) return;
    const float* wr = Wf + (size_t)wrow * H_;
    short* wb = Wb + (size_t)wrow * H_;
    float acc = 0.f;
    for (int k4 = lane * 4; k4 < H_; k4 += 256) {
        float4 w  = *(const float4*)(wr + k4);
        float4 sc = *(const float4*)(scale + k4);
        float4 sh = *(const float4*)(shift + k4);
        short4 s;
        s.x = f2bf(w.x * sc.x); s.y = f2bf(w.y * sc.y);
        s.z = f2bf(w.z * sc.z); s.w = f2bf(w.w * sc.w);
        *(short4*)(wb + k4) = s;
        acc += w.x * sh.x + w.y * sh.y + w.z * sh.z + w.w * sh.w;
    }
#pragma unroll
    for (int o = 32; o > 0; o >>= 1) acc += __shfl_down(acc, o);
    if (lane == 0) bias2[wrow] = acc + b[wrow];
}

// ---------------------------------------------------------------------------
// fp32 [rows][K0REAL] -> bf16 [rows][K0PAD] zero-padded
// ---------------------------------------------------------------------------
__global__ __launch_bounds__(256) void conv_pad(
    const float* __restrict__ X, short* __restrict__ Xb, int rows)
{
    const int npr = K0PAD / 4;   // 40
    const int idx = blockIdx.x * blockDim.x + threadIdx.x;
    if (idx >= rows * npr) return;
    const int r = idx / npr;
    const int c4 = (idx - r * npr) * 4;
    short4 s = {0, 0, 0, 0};
    if (c4 < K0REAL) {
        float4 v = *(const float4*)(X + (size_t)r * K0REAL + c4);
        s.x = f2bf(v.x); s.y = f2bf(v.y); s.z = f2bf(v.z); s.w = f2bf(v.w);
    }
    *(short4*)(Xb + (size_t)r * K0PAD + c4) = s;
}

// ---------------------------------------------------------------------------
// out[b,c] = sum_h (bf2f(Hb[b,h])*scale[h]+shift[h]) * Wlast[c,h] + blast[c]
// ---------------------------------------------------------------------------
__global__ __launch_bounds__(256) void final_proj(
    const short* __restrict__ Hb, const float* __restrict__ scale,
    const float* __restrict__ shift, const float* __restrict__ Wlast,
    const float* __restrict__ blast, float* __restrict__ out)
{
    const int wave = (blockIdx.x * blockDim.x + threadIdx.x) >> 6;
    const int lane = threadIdx.x & 63;
    if (wave >= B_ * C_) return;
    const int b = wave / C_;
    const int c = wave % C_;
    float acc = 0.f;
    for (int h = lane; h < H_; h += 64) {
        float hv = bf2f(Hb[(size_t)b * H_ + h]) * scale[h] + shift[h];
        acc += hv * Wlast[(size_t)c * H_ + h];
    }
#pragma unroll
    for (int o = 32; o > 0; o >>= 1) acc += __shfl_down(acc, o);
    if (lane == 0) out[(size_t)b * C_ + c] = acc + blast[c];
}

// ---------------------------------------------------------------------------
extern "C" void kernel_launch(void* const* d_in, const int* in_sizes, int n_in,
                              void* d_out, int out_size, void* d_ws, size_t ws_size,
                              hipStream_t stream)
{
    const float* x      = (const float*)d_in[0];  // [8192,144]
    const float* W0     = (const float*)d_in[1];  // [2048,144]
    const float* Ws     = (const float*)d_in[2];  // [3,2048,2048]
    const float* bs     = (const float*)d_in[3];  // [4,2048]
    const float* us     = (const float*)d_in[4];
    const float* gammas = (const float*)d_in[5];
    const float* betas  = (const float*)d_in[6];
    const float* Wlast  = (const float*)d_in[7];  // [10,2048]
    const float* blast  = (const float*)d_in[8];
    float* out = (float*)d_out;

    char* ws = (char*)d_ws;
    float* buf0    = (float*)ws;                            // 64 MB fp32 z
    short* Ab      = (short*)(ws + (size_t)64  * 1048576);  // 32 MB bf16 h
    short* Wb      = (short*)(ws + (size_t)96  * 1048576);  // 8 MB folded W
    short* X0b     = (short*)(ws + (size_t)104 * 1048576);  // 2.56 MB
    short* W0b     = (short*)(ws + (size_t)107 * 1048576);  // 0.64 MB
    float* sum     = (float*)(ws + (size_t)108 * 1048576);
    float* sumsq   = sum + H_;
    float* bnscale = sumsq + H_;
    float* bnshift = bnscale + H_;
    float* bias2   = bnshift + H_;

    const int M = T_ * B_;   // 8192

    conv_pad<<<(M * (K0PAD / 4) + 255) / 256, 256, 0, stream>>>(x, X0b, M);
    conv_pad<<<(H_ * (K0PAD / 4) + 255) / 256, 256, 0, stream>>>(W0, W0b, H_);

    // layer 0 projection (K padded to 160): proven 128^2 kernel
    gemm_bf16_lds<<<dim3(H_ / 128, M / 128), 256, 0, stream>>>(
        X0b, W0b, bs, buf0, M, H_, K0PAD);

    const dim3 g256(M / 256, H_ / 256);   // (32, 8) = 256 blocks
    for (int l = 0; l < L_; ++l) {
        hipMemsetAsync(sum, 0, 2 * H_ * sizeof(float), stream);
        scan_bf16<<<(B_ * H_) / 256, 256, 0, stream>>>(buf0, us + l * H_, Ab, sum, sumsq);
        bn_finalize<<<H_ / 256, 256, 0, stream>>>(sum, sumsq,
                                                  gammas + l * H_, betas + l * H_,
                                                  bnscale, bnshift);
        if (l < L_ - 1) {
            const float* Wl = Ws + (size_t)l * H_ * H_;
            fold_wb<<<(H_ * 64) / 256, 256, 0, stream>>>(Wl, bnscale, bnshift,
                                                         bs + (l + 1) * H_, Wb, bias2);
            gemm_bf16_8ph<<<g256, 512, 0, stream>>>(Ab, Wb, bias2, buf0, M, H_, H_);
        }
    }

    final_proj<<<(B_ * C_ * 64 + 255) / 256, 256, 0, stream>>>(
        Ab + (size_t)(T_ - 1) * B_ * H_, bnscale, bnshift, Wlast, blast, out);
}